// Round 9
// baseline (384.544 us; speedup 1.0000x reference)
//
#include <hip/hip_runtime.h>
#include <hip/hip_bf16.h>

typedef float fv4 __attribute__((ext_vector_type(4)));
typedef unsigned uv4 __attribute__((ext_vector_type(4)));
typedef unsigned uv2 __attribute__((ext_vector_type(2)));
using f32x2 = __attribute__((ext_vector_type(2))) float;
using bf8   = __attribute__((ext_vector_type(8))) short;  // 8 bf16 = 4 VGPRs (MFMA A/B frag)
using f32x4 = __attribute__((ext_vector_type(4))) float;  // MFMA C/D frag

#define HDIM 64

// round-to-nearest-even fp32 -> bf16 bits (prep path)
__device__ __forceinline__ unsigned bf16r(float f) {
    unsigned u = __float_as_uint(f);
    return (u + 0x7fffu + ((u >> 16) & 1u)) >> 16;
}
__device__ __forceinline__ float bfs2f(unsigned short s) { return __uint_as_float(((unsigned)s) << 16); }

// pack two fp32 -> bf16 pair, round-half-up
__device__ __forceinline__ unsigned pack_pair(float f0, float f1) {
    unsigned p0 = __float_as_uint(f0) + 0x8000u;
    unsigned p1 = __float_as_uint(f1) + 0x8000u;
    return (p0 >> 16) | (p1 & 0xffff0000u);
}

// 4 packed fp8 e4m3 -> 4 floats (hw v_cvt_pk_f32_fp8)
__device__ __forceinline__ void fp8x4_to_f32(unsigned w, float* f) {
    f32x2 lo = __builtin_amdgcn_cvt_pk_f32_fp8((int)w, false);
    f32x2 hi = __builtin_amdgcn_cvt_pk_f32_fp8((int)w, true);
    f[0] = lo[0]; f[1] = lo[1]; f[2] = hi[0]; f[3] = hi[1];
}
// 4 floats -> packed fp8 e4m3 (hw v_cvt_pk_fp8_f32)
__device__ __forceinline__ unsigned f32x4_to_fp8(float a, float b, float c, float d) {
    int w = 0;
    w = __builtin_amdgcn_cvt_pk_fp8_f32(a, b, w, false);
    w = __builtin_amdgcn_cvt_pk_fp8_f32(c, d, w, true);
    return (unsigned)w;
}

// ---------------------------------------------------------------------------
// pre1 (+ fused prep): u1 = [x|pos]@(W1a-W1b)+b1 (bf16); v1 = [x|pos]@W1b (fp8).
// Low blocks additionally build the W2 hi/lo tables, the conv2 combined
// pre-weight Wpre[c'][d], and zero qsums/qcnt (absorbs the old prep dispatch).
// ---------------------------------------------------------------------------
__global__ void pre1_kernel(
    const float* __restrict__ x, const float* __restrict__ pos,
    const float* __restrict__ W1, const float* __restrict__ b1,
    const float* __restrict__ W2a, const float* __restrict__ W2b,
    const float* __restrict__ W1c,
    unsigned short* __restrict__ hiA, unsigned short* __restrict__ loA,
    unsigned short* __restrict__ hiB, unsigned short* __restrict__ loB,
    unsigned short* __restrict__ wph, unsigned short* __restrict__ wpl,
    float* __restrict__ qsums, int* __restrict__ qcnt,
    unsigned short* __restrict__ U, unsigned char* __restrict__ Vf8, int N)
{
    int gidx = blockIdx.x * 256 + threadIdx.x;
    if (gidx < 512) qsums[gidx] = 0.f;
    if (gidx < 8)   qcnt[gidx]  = 0;
    if (gidx < 4096) {
        int j = gidx >> 6, c = gidx & 63;
        float w = W2a[gidx];
        unsigned h = bf16r(w);
        unsigned l = bf16r(w - __uint_as_float(h << 16));
        hiA[c * 64 + j] = (unsigned short)h; loA[c * 64 + j] = (unsigned short)l;
        w = W2b[gidx];
        h = bf16r(w);
        l = bf16r(w - __uint_as_float(h << 16));
        hiB[c * 64 + j] = (unsigned short)h; loB[c * 64 + j] = (unsigned short)l;
    }
    if (gidx < 8192) {
        int d = gidx & 63, cp = gidx >> 6;
        float w = (cp < 64) ? (W1c[d * 64 + cp] - W1c[(d + 64) * 64 + cp])
                            : W1c[(d + 64) * 64 + (cp - 64)];
        unsigned h = bf16r(w);
        unsigned l = bf16r(w - __uint_as_float(h << 16));
        wph[cp * 64 + d] = (unsigned short)h;
        wpl[cp * 64 + d] = (unsigned short)l;
    }

    int lane = threadIdx.x & 63;
    int gw   = gidx >> 6;
    int tw   = (gridDim.x * blockDim.x) >> 6;

    float wd[19], wb[19];
#pragma unroll
    for (int d = 0; d < 19; ++d) {
        float a = W1[d * HDIM + lane];
        float b = W1[(d + 19) * HDIM + lane];
        wd[d] = a - b;
        wb[d] = b;
    }
    float bb = b1[lane];

    for (int n = gw; n < N; n += 2 * tw) {
        int n2 = n + tw; if (n2 >= N) n2 = n;   // clamp: benign duplicate
        fv4 hA[4], hB[4];
#pragma unroll
        for (int d4 = 0; d4 < 4; ++d4) {
            hA[d4] = __builtin_nontemporal_load((const fv4*)&x[(size_t)n  * 16 + 4 * d4]);
            hB[d4] = __builtin_nontemporal_load((const fv4*)&x[(size_t)n2 * 16 + 4 * d4]);
        }
        float pA[3], pB[3];
#pragma unroll
        for (int d = 0; d < 3; ++d) {
            pA[d] = pos[(size_t)n  * 3 + d];
            pB[d] = pos[(size_t)n2 * 3 + d];
        }
        float suA = 0.f, svA = 0.f, suB = 0.f, svB = 0.f;
#pragma unroll
        for (int d4 = 0; d4 < 4; ++d4)
#pragma unroll
            for (int k = 0; k < 4; ++k) {
                suA += hA[d4][k] * wd[4 * d4 + k];
                svA += hA[d4][k] * wb[4 * d4 + k];
                suB += hB[d4][k] * wd[4 * d4 + k];
                svB += hB[d4][k] * wb[4 * d4 + k];
            }
#pragma unroll
        for (int d = 0; d < 3; ++d) {
            suA += pA[d] * wd[16 + d];  svA += pA[d] * wb[16 + d];
            suB += pB[d] * wd[16 + d];  svB += pB[d] * wb[16 + d];
        }
        U[(size_t)n  * HDIM + lane] = (unsigned short)bf16r(suA + bb);
        U[(size_t)n2 * HDIM + lane] = (unsigned short)bf16r(suB + bb);
        Vf8[(size_t)n  * HDIM + lane] =
            (unsigned char)(__builtin_amdgcn_cvt_pk_fp8_f32(svA, svA, 0, false) & 0xff);
        Vf8[(size_t)n2 * HDIM + lane] =
            (unsigned char)(__builtin_amdgcn_cvt_pk_fp8_f32(svB, svB, 0, false) & 0xff);
    }
}

// ---------------------------------------------------------------------------
// edge_pre_fused: conv1 edge-conv + conv2 layer-1 GEMM, fused.
// Phase A (edge): wave = 4 nodes = 64 edges, fp8-V gather + bf16 MFMA, h1
// goes to a pad-strided LDS tile (NEVER to global: saves 12.5MB W + 12.8MB R
// and the pre_mfma dispatch). Phase B (pre): the block's 16 nodes are one
// GEMM tile; wave w computes output chunks nt=2w,2w+1 (8 MFMAs) from the LDS
// tile, writing U2 (bf16, +bias) / V2 (fp8).
// LDS: 16 rows x 72 shorts (144B stride: 36 dwords -> rows m,m+8 share banks
// = 2-way, free). h1 numerics identical to R8 (same bf16 round points).
// ---------------------------------------------------------------------------
__global__ __launch_bounds__(256, 2) void edge_pre_fused_kernel(
    const unsigned short* __restrict__ U1, const unsigned char* __restrict__ V1,
    const int* __restrict__ src,
    const unsigned short* __restrict__ W2hi, const unsigned short* __restrict__ W2lo,
    const float* __restrict__ b12,
    const unsigned short* __restrict__ Wphi, const unsigned short* __restrict__ Wplo,
    const float* __restrict__ b21,
    unsigned short* __restrict__ U2, unsigned char* __restrict__ V2)
{
    __shared__ __align__(16) unsigned short hs[16 * 72];

    int tid  = threadIdx.x;
    int wave = tid >> 6;
    int lane = tid & 63;
    int quad = lane >> 4;
    int m    = lane & 15;

    int nodeBase  = blockIdx.x * 16 + wave * 4;
    long edgeBase = (long)nodeBase * 16;

    int sArr[4];
#pragma unroll
    for (int mt = 0; mt < 4; ++mt)
        sArr[mt] = __builtin_nontemporal_load(&src[edgeBase + mt * 16 + m]);

    // hoisted: fp8 V gathers (8B) + NT U rows (16B)
    uv2 v0[4], v1[4];
    uv4 u0[4], u1[4];
#pragma unroll
    for (int mt = 0; mt < 4; ++mt) {
        size_t sRow = (size_t)sArr[mt] * HDIM;       // byte offset (64B rows)
        v0[mt] = *(const uv2*)&V1[sRow + quad * 8];
        v1[mt] = *(const uv2*)&V1[sRow + 32 + quad * 8];
    }
#pragma unroll
    for (int mt = 0; mt < 4; ++mt) {
        size_t tRow = (size_t)(nodeBase + mt) * HDIM;
        u0[mt] = __builtin_nontemporal_load((const uv4*)&U1[tRow + quad * 8]);
        u1[mt] = __builtin_nontemporal_load((const uv4*)&U1[tRow + 32 + quad * 8]);
    }

    // phase-B A-frags (Wpre, L2-hot) hoisted to overlap with the gathers
    int nt0 = wave * 2;
    bf8 PAh[2][2], PAl[2][2];
#pragma unroll
    for (int j = 0; j < 2; ++j)
#pragma unroll
        for (int ks = 0; ks < 2; ++ks) {
            int off = ((nt0 + j) * 16 + m) * 64 + ks * 32 + quad * 8;
            PAh[j][ks] = *(const bf8*)&Wphi[off];
            PAl[j][ks] = *(const bf8*)&Wplo[off];
        }

    // W2 B-frags
    bf8 Bh[4][2], Bl[4][2];
#pragma unroll
    for (int nt = 0; nt < 4; ++nt)
#pragma unroll
        for (int ks = 0; ks < 2; ++ks) {
            int off = (nt * 16 + m) * 64 + ks * 32 + quad * 8;
            Bh[nt][ks] = *(const bf8*)&W2hi[off];
            Bl[nt][ks] = *(const bf8*)&W2lo[off];
        }
    float b2v = b12[lane];

    // ---- phase A: edge conv -> h1 into LDS ----
#pragma unroll
    for (int mt = 0; mt < 4; ++mt) {
        float vf0[8], vf1[8];
        fp8x4_to_f32(v0[mt][0], &vf0[0]);
        fp8x4_to_f32(v0[mt][1], &vf0[4]);
        fp8x4_to_f32(v1[mt][0], &vf1[0]);
        fp8x4_to_f32(v1[mt][1], &vf1[4]);

        uv4 a0, a1;
#pragma unroll
        for (int d = 0; d < 4; ++d) {
            unsigned ud0 = u0[mt][d], ud1 = u1[mt][d];
            float r0 = fmaxf(__uint_as_float(ud0 << 16)         + vf0[2 * d],     0.f);
            float r1 = fmaxf(__uint_as_float(ud0 & 0xffff0000u) + vf0[2 * d + 1], 0.f);
            float r2 = fmaxf(__uint_as_float(ud1 << 16)         + vf1[2 * d],     0.f);
            float r3 = fmaxf(__uint_as_float(ud1 & 0xffff0000u) + vf1[2 * d + 1], 0.f);
            a0[d] = pack_pair(r0, r1);
            a1[d] = pack_pair(r2, r3);
        }
        bf8 A0 = *(bf8*)&a0;
        bf8 A1 = *(bf8*)&a1;

        f32x4 acc[4] = {{0,0,0,0},{0,0,0,0},{0,0,0,0},{0,0,0,0}};
#pragma unroll
        for (int nt = 0; nt < 4; ++nt) {
            acc[nt] = __builtin_amdgcn_mfma_f32_16x16x32_bf16(A0, Bl[nt][0], acc[nt], 0, 0, 0);
            acc[nt] = __builtin_amdgcn_mfma_f32_16x16x32_bf16(A0, Bh[nt][0], acc[nt], 0, 0, 0);
            acc[nt] = __builtin_amdgcn_mfma_f32_16x16x32_bf16(A1, Bl[nt][1], acc[nt], 0, 0, 0);
            acc[nt] = __builtin_amdgcn_mfma_f32_16x16x32_bf16(A1, Bh[nt][1], acc[nt], 0, 0, 0);
        }

        float mx[4];
#pragma unroll
        for (int nt = 0; nt < 4; ++nt)
            mx[nt] = fmaxf(fmaxf(acc[nt][0], acc[nt][1]), fmaxf(acc[nt][2], acc[nt][3]));
#pragma unroll
        for (int nt = 0; nt < 4; ++nt) {
            mx[nt] = fmaxf(mx[nt], __shfl_xor(mx[nt], 16));
            mx[nt] = fmaxf(mx[nt], __shfl_xor(mx[nt], 32));
        }
        float val = (quad == 0) ? mx[0] : (quad == 1) ? mx[1] : (quad == 2) ? mx[2] : mx[3];
        unsigned p = (__float_as_uint(fmaxf(val + b2v, 0.f)) + 0x8000u) >> 16;
        hs[(wave * 4 + mt) * 72 + lane] = (unsigned short)p;  // channel = lane
    }
    __syncthreads();

    // ---- phase B: [16 x 64] @ Wpre^T for this block's tile ----
    bf8 PB0 = *(const bf8*)((const char*)hs + m * 144 + quad * 16);        // k<32
    bf8 PB1 = *(const bf8*)((const char*)hs + m * 144 + 64 + quad * 16);   // k>=32

    f32x4 pacc[2] = {{0,0,0,0},{0,0,0,0}};
#pragma unroll
    for (int j = 0; j < 2; ++j) {
        pacc[j] = __builtin_amdgcn_mfma_f32_16x16x32_bf16(PAl[j][0], PB0, pacc[j], 0, 0, 0);
        pacc[j] = __builtin_amdgcn_mfma_f32_16x16x32_bf16(PAh[j][0], PB0, pacc[j], 0, 0, 0);
        pacc[j] = __builtin_amdgcn_mfma_f32_16x16x32_bf16(PAl[j][1], PB1, pacc[j], 0, 0, 0);
        pacc[j] = __builtin_amdgcn_mfma_f32_16x16x32_bf16(PAh[j][1], PB1, pacc[j], 0, 0, 0);
    }

    // D layout: col(lane&15)=node m, row(quad*4+r)=channel within chunk
    size_t nodeRow = (size_t)(blockIdx.x * 16 + m) * HDIM;
#pragma unroll
    for (int j = 0; j < 2; ++j) {
        int nt = nt0 + j;
        f32x4 v = pacc[j];
        int cc = (nt & 3) * 16 + quad * 4;
        if (nt < 4) {
            fv4 bias = *(const fv4*)&b21[nt * 16 + quad * 4];
#pragma unroll
            for (int r = 0; r < 4; ++r) v[r] += bias[r];
            unsigned* p = (unsigned*)&U2[nodeRow + cc];
            p[0] = pack_pair(v[0], v[1]);
            p[1] = pack_pair(v[2], v[3]);
        } else {
            *(unsigned*)&V2[nodeRow + cc] = f32x4_to_fp8(v[0], v[1], v[2], v[3]);
        }
    }
}

// ---------------------------------------------------------------------------
// edge_mfma (conv2): unchanged R8 structure; writes h2 bf16.
// ---------------------------------------------------------------------------
__global__ __launch_bounds__(256, 2) void edge_mfma_kernel(
    const unsigned short* __restrict__ U, const unsigned char* __restrict__ Vf8,
    const int* __restrict__ src,
    const unsigned short* __restrict__ Whi, const unsigned short* __restrict__ Wlo,
    const float* __restrict__ b2, unsigned short* __restrict__ out)
{
    int tid  = threadIdx.x;
    int wave = tid >> 6;
    int lane = tid & 63;
    int quad = lane >> 4;
    int m    = lane & 15;

    int nodeBase  = blockIdx.x * 16 + wave * 4;
    long edgeBase = (long)nodeBase * 16;

    int sArr[4];
#pragma unroll
    for (int mt = 0; mt < 4; ++mt)
        sArr[mt] = __builtin_nontemporal_load(&src[edgeBase + mt * 16 + m]);

    uv2 v0[4], v1[4];
    uv4 u0[4], u1[4];
#pragma unroll
    for (int mt = 0; mt < 4; ++mt) {
        size_t sRow = (size_t)sArr[mt] * HDIM;
        v0[mt] = *(const uv2*)&Vf8[sRow + quad * 8];
        v1[mt] = *(const uv2*)&Vf8[sRow + 32 + quad * 8];
    }
#pragma unroll
    for (int mt = 0; mt < 4; ++mt) {
        size_t tRow = (size_t)(nodeBase + mt) * HDIM;
        u0[mt] = __builtin_nontemporal_load((const uv4*)&U[tRow + quad * 8]);
        u1[mt] = __builtin_nontemporal_load((const uv4*)&U[tRow + 32 + quad * 8]);
    }

    bf8 Bh[4][2], Bl[4][2];
#pragma unroll
    for (int nt = 0; nt < 4; ++nt)
#pragma unroll
        for (int ks = 0; ks < 2; ++ks) {
            int off = (nt * 16 + m) * 64 + ks * 32 + quad * 8;
            Bh[nt][ks] = *(const bf8*)&Whi[off];
            Bl[nt][ks] = *(const bf8*)&Wlo[off];
        }
    float b2v = b2[lane];

#pragma unroll
    for (int mt = 0; mt < 4; ++mt) {
        float vf0[8], vf1[8];
        fp8x4_to_f32(v0[mt][0], &vf0[0]);
        fp8x4_to_f32(v0[mt][1], &vf0[4]);
        fp8x4_to_f32(v1[mt][0], &vf1[0]);
        fp8x4_to_f32(v1[mt][1], &vf1[4]);

        uv4 a0, a1;
#pragma unroll
        for (int d = 0; d < 4; ++d) {
            unsigned ud0 = u0[mt][d], ud1 = u1[mt][d];
            float r0 = fmaxf(__uint_as_float(ud0 << 16)         + vf0[2 * d],     0.f);
            float r1 = fmaxf(__uint_as_float(ud0 & 0xffff0000u) + vf0[2 * d + 1], 0.f);
            float r2 = fmaxf(__uint_as_float(ud1 << 16)         + vf1[2 * d],     0.f);
            float r3 = fmaxf(__uint_as_float(ud1 & 0xffff0000u) + vf1[2 * d + 1], 0.f);
            a0[d] = pack_pair(r0, r1);
            a1[d] = pack_pair(r2, r3);
        }
        bf8 A0 = *(bf8*)&a0;
        bf8 A1 = *(bf8*)&a1;

        f32x4 acc[4] = {{0,0,0,0},{0,0,0,0},{0,0,0,0},{0,0,0,0}};
#pragma unroll
        for (int nt = 0; nt < 4; ++nt) {
            acc[nt] = __builtin_amdgcn_mfma_f32_16x16x32_bf16(A0, Bl[nt][0], acc[nt], 0, 0, 0);
            acc[nt] = __builtin_amdgcn_mfma_f32_16x16x32_bf16(A0, Bh[nt][0], acc[nt], 0, 0, 0);
            acc[nt] = __builtin_amdgcn_mfma_f32_16x16x32_bf16(A1, Bl[nt][1], acc[nt], 0, 0, 0);
            acc[nt] = __builtin_amdgcn_mfma_f32_16x16x32_bf16(A1, Bh[nt][1], acc[nt], 0, 0, 0);
        }

        float mx[4];
#pragma unroll
        for (int nt = 0; nt < 4; ++nt)
            mx[nt] = fmaxf(fmaxf(acc[nt][0], acc[nt][1]), fmaxf(acc[nt][2], acc[nt][3]));
#pragma unroll
        for (int nt = 0; nt < 4; ++nt) {
            mx[nt] = fmaxf(mx[nt], __shfl_xor(mx[nt], 16));
            mx[nt] = fmaxf(mx[nt], __shfl_xor(mx[nt], 32));
        }
        float val = (quad == 0) ? mx[0] : (quad == 1) ? mx[1] : (quad == 2) ? mx[2] : mx[3];
        unsigned p = (__float_as_uint(fmaxf(val + b2v, 0.f)) + 0x8000u) >> 16;
        out[(size_t)(nodeBase + mt) * HDIM + lane] = (unsigned short)p;
    }
}

// ---------------------------------------------------------------------------
// region mean accumulation (bf16 input)
// ---------------------------------------------------------------------------
__global__ void region_mean_kernel(const unsigned short* __restrict__ h,
                                   const int* __restrict__ labels,
                                   float* __restrict__ qsums, int* __restrict__ qcnt, int N)
{
    __shared__ float ls[8 * 64];
    __shared__ int   lc[8];
    int tid  = threadIdx.x;
    int lane = tid & 63;
    int gw   = (blockIdx.x * blockDim.x + tid) >> 6;
    int tw   = (gridDim.x * blockDim.x) >> 6;

    float acc[8] = {0, 0, 0, 0, 0, 0, 0, 0};
    int   cnt[8] = {0, 0, 0, 0, 0, 0, 0, 0};

    for (int n = gw; n < N; n += tw) {
        int lbl = labels[n];
        float val = bfs2f(h[(size_t)n * HDIM + lane]);
#pragma unroll
        for (int r = 0; r < 8; ++r) {
            acc[r] += (lbl == r) ? val : 0.f;
            cnt[r] += (lbl == r) ? 1 : 0;
        }
    }

    if (tid < 8) lc[tid] = 0;
    for (int idx = tid; idx < 512; idx += 256) ls[idx] = 0.f;
    __syncthreads();
#pragma unroll
    for (int r = 0; r < 8; ++r) atomicAdd(&ls[r * 64 + lane], acc[r]);
    if (lane == 0)
#pragma unroll
        for (int r = 0; r < 8; ++r) atomicAdd(&lc[r], cnt[r]);
    __syncthreads();
    for (int idx = tid; idx < 512; idx += 256) atomicAdd(&qsums[idx], ls[idx]);
    if (tid < 8) atomicAdd(&qcnt[tid], lc[tid]);
}

// ---------------------------------------------------------------------------
// tail: fully parallel quotient convs (8 nodes, 32 edges) + pool + linear.
// ---------------------------------------------------------------------------
#define EQ_MAX 64
__global__ void tail_kernel(const float* __restrict__ qsums, const int* __restrict__ qcnt,
                            const int* __restrict__ qei, int Eq,
                            const float* __restrict__ W31, const float* __restrict__ b31,
                            const float* __restrict__ W32, const float* __restrict__ b32,
                            const float* __restrict__ W41, const float* __restrict__ b41,
                            const float* __restrict__ W42, const float* __restrict__ b42,
                            const float* __restrict__ linW, const float* __restrict__ linb,
                            float* __restrict__ out)
{
    __shared__ float qx[512], uu[512], vv[512];
    __shared__ float hr[EQ_MAX * 64], me[EQ_MAX * 64];
    __shared__ __align__(16) float W2s[64 * 64];
    __shared__ int   qes[EQ_MAX], qet[EQ_MAX];
    __shared__ float emb[64];

    int tid = threadIdx.x;
    if (Eq > EQ_MAX) Eq = EQ_MAX;

    if (tid < Eq) { qes[tid] = qei[tid]; qet[tid] = qei[Eq + tid]; }
    for (int idx = tid; idx < 512; idx += 256) {
        int r = idx >> 6;
        int cc = qcnt[r];
        qx[idx] = (cc > 0) ? qsums[idx] / (float)cc : 0.f;
    }
    __syncthreads();

    for (int layer = 0; layer < 2; ++layer) {
        const float* W1p = layer ? W41 : W31;
        const float* b1p = layer ? b41 : b31;
        const float* W2p = layer ? W42 : W32;
        const float* b2p = layer ? b42 : b32;

        for (int idx = tid * 4; idx < 4096; idx += 1024)
            *(fv4*)&W2s[idx] = *(const fv4*)&W2p[idx];

        for (int idx = tid; idx < 512; idx += 256) {
            int t = idx >> 6, c = idx & 63;
            float su = 0.f, sv = 0.f;
#pragma unroll 8
            for (int d = 0; d < 64; ++d) {
                float hv = qx[t * 64 + d];
                float a = W1p[d * 64 + c];
                float b = W1p[(d + 64) * 64 + c];
                su += hv * (a - b);
                sv += hv * b;
            }
            uu[idx] = su + b1p[c];
            vv[idx] = sv;
        }
        __syncthreads();

        for (int idx = tid; idx < Eq * 64; idx += 256) {
            int e = idx >> 6, c = idx & 63;
            hr[idx] = fmaxf(uu[qet[e] * 64 + c] + vv[qes[e] * 64 + c], 0.f);
        }
        __syncthreads();

        {
            int c = tid & 63, e0 = tid >> 6;
            for (int e = e0; e < Eq; e += 4) {
                float acc = 0.f;
#pragma unroll 8
                for (int j = 0; j < 64; ++j)
                    acc += hr[e * 64 + j] * W2s[j * 64 + c];
                me[e * 64 + c] = acc;
            }
        }
        __syncthreads();

        for (int idx = tid; idx < 512; idx += 256) {
            int t = idx >> 6, c = idx & 63;
            float a = -INFINITY;
            for (int e = 0; e < Eq; ++e)
                if (qet[e] == t) a = fmaxf(a, me[e * 64 + c]);
            float vout = (a == -INFINITY) ? 0.f : (a + b2p[c]);
            qx[idx] = fmaxf(vout, 0.f);
        }
        __syncthreads();
    }

    if (tid < 64) {
        float s = 0.f;
        for (int r = 0; r < 8; ++r) s += qx[r * 64 + tid];
        emb[tid] = s;
    }
    __syncthreads();
    if (tid < 8) {
        float o = linb[tid];
        for (int c = 0; c < 64; ++c) o += emb[c] * linW[c * 8 + tid];
        out[tid] = o;
    }
}

// ---------------------------------------------------------------------------
extern "C" void kernel_launch(void* const* d_in, const int* in_sizes, int n_in,
                              void* d_out, int out_size, void* d_ws, size_t ws_size,
                              hipStream_t stream)
{
    const float* x    = (const float*)d_in[0];
    const float* pos  = (const float*)d_in[1];
    const int*   ei   = (const int*)d_in[2];
    const int*   lbl  = (const int*)d_in[3];
    const int*   qei  = (const int*)d_in[4];
    const float* W11 = (const float*)d_in[5];
    const float* b11 = (const float*)d_in[6];
    const float* W12 = (const float*)d_in[7];
    const float* b12 = (const float*)d_in[8];
    const float* W21 = (const float*)d_in[9];
    const float* b21 = (const float*)d_in[10];
    const float* W22 = (const float*)d_in[11];
    const float* b22 = (const float*)d_in[12];
    const float* W31 = (const float*)d_in[13];
    const float* b31 = (const float*)d_in[14];
    const float* W32 = (const float*)d_in[15];
    const float* b32 = (const float*)d_in[16];
    const float* W41 = (const float*)d_in[17];
    const float* b41 = (const float*)d_in[18];
    const float* W42 = (const float*)d_in[19];
    const float* b42 = (const float*)d_in[20];
    const float* linW = (const float*)d_in[21];
    const float* linb = (const float*)d_in[22];

    int N  = in_sizes[0] / 16;          // 100000
    int Eq = in_sizes[4] / 2;           // 32
    const int* src = ei;                // row 0 = src; tgt = repeat(arange(N),16)

    size_t NH = (size_t)N * HDIM;
    unsigned short* U1  = (unsigned short*)d_ws;       // bf16 N*64; reused as h2
    unsigned char*  V1  = (unsigned char*)(U1 + NH);   // fp8 N*64
    unsigned short* U2  = (unsigned short*)(V1 + NH);  // bf16 N*64
    unsigned char*  V2  = (unsigned char*)(U2 + NH);   // fp8 N*64
    unsigned short* w2h1 = (unsigned short*)(V2 + NH);
    unsigned short* w2l1 = w2h1 + 4096;
    unsigned short* w2h2 = w2l1 + 4096;
    unsigned short* w2l2 = w2h2 + 4096;
    unsigned short* wph  = w2l2 + 4096;                // 8192
    unsigned short* wpl  = wph + 8192;                 // 8192
    float* qsums = (float*)(wpl + 8192);
    int*   qcnt  = (int*)(qsums + 512);
    unsigned short* h2 = U1;                           // alias (U1 dead after fused)

    int edgeBlocks = N / 16;            // 6250

    // conv1 pre (+prep tables +qsums zero)
    pre1_kernel<<<2048, 256, 0, stream>>>(x, pos, W11, b11, W12, W22, W21,
                                          w2h1, w2l1, w2h2, w2l2, wph, wpl,
                                          qsums, qcnt, U1, V1, N);
    // conv1 edge + conv2 pre, fused
    edge_pre_fused_kernel<<<edgeBlocks, 256, 0, stream>>>(
        U1, V1, src, w2h1, w2l1, b12, wph, wpl, b21, U2, V2);
    // conv2 edge
    edge_mfma_kernel<<<edgeBlocks, 256, 0, stream>>>(U2, V2, src, w2h2, w2l2, b22, h2);
    // quotient pooling + tail
    region_mean_kernel<<<1024, 256, 0, stream>>>(h2, lbl, qsums, qcnt, N);
    tail_kernel<<<1, 256, 0, stream>>>(qsums, qcnt, qei, Eq,
                                       W31, b31, W32, b32,
                                       W41, b41, W42, b42,
                                       linW, linb, (float*)d_out);
}